// Round 2
// baseline (3340.978 us; speedup 1.0000x reference)
//
#include <hip/hip_runtime.h>
#include <hip/hip_bf16.h>

#define B_TOT  32768
#define M_TOK  200
#define NL     22
#define OWW    11
#define PLANE  121        // 11*11
#define FEAT_N (NL*PLANE) // 2662
#define CH     128
#define HIDDEN 512

// One block per sample. All float tensors are fp32; observations int32.
extern "C" __global__ __launch_bounds__(256)
void policy_fwd(const int* __restrict__ obs,
                const float* __restrict__ maxvec,
                const float* __restrict__ wc1,
                const float* __restrict__ bc1,
                const float* __restrict__ wc2,
                const float* __restrict__ bc2,
                const float* __restrict__ wfc,
                const float* __restrict__ bfc,
                const float* __restrict__ wself,
                const float* __restrict__ bself,
                const float* __restrict__ wa0,
                const float* __restrict__ ba0,
                const float* __restrict__ wa1,
                const float* __restrict__ ba1,
                const float* __restrict__ wv,
                const float* __restrict__ bv,
                float* __restrict__ out)
{
  __shared__ int   toks[M_TOK*3];
  __shared__ int   boxi[FEAT_N];   // packed (m<<8)|val, -1 = empty
  __shared__ float feat[FEAT_N];
  __shared__ float h1[CH*9];
  __shared__ float p1[CH*9];       // partial accum buffer (reused by conv2)
  __shared__ float h2[CH];
  __shared__ float hid[HIDDEN];
  __shared__ float maxv[NL];

  const int tid = threadIdx.x;
  const int b   = blockIdx.x;

  // ---- load tokens, init box ----
  const int* op = obs + (long)b * (M_TOK*3);
  for (int i = tid; i < M_TOK*3; i += 256) toks[i] = op[i];
  for (int i = tid; i < FEAT_N; i += 256) boxi[i] = -1;
  if (tid < NL) maxv[tid] = maxvec[tid];
  __syncthreads();

  // ---- scatter: last-write-wins via atomicMax on (m<<8)|val ----
  if (tid < M_TOK) {
    int c = toks[tid*3+0]; c = (c==255) ? 0 : c;
    int a = toks[tid*3+1]; a = (a==255) ? 0 : a;
    int v = toks[tid*3+2]; v = (v==255) ? 0 : v;
    int x = (c >> 4) & 15, y = c & 15;
    if (x < OWW && y < OWW && a < NL)
      atomicMax(&boxi[a*PLANE + x*OWW + y], (tid << 8) | v);
  }
  __syncthreads();

  // ---- features = box / max_vec ----
  for (int i = tid; i < FEAT_N; i += 256) {
    int a  = i / PLANE;
    int pv = boxi[i];
    float val = (pv >= 0) ? (float)(pv & 255) : 0.0f;
    feat[i] = val / maxv[a];
  }
  __syncthreads();

  // ---- self head: hid[0:256] = relu(feat[:,5,5] @ w_self + b_self) ----
  {
    float acc = bself[tid];
    #pragma unroll
    for (int a = 0; a < NL; a++)
      acc = fmaf(feat[a*PLANE + 60], wself[a*256 + tid], acc);
    hid[tid] = fmaxf(acc, 0.0f);
  }

  // ---- conv1: 22ch 11x11 -> 128ch 3x3 (5x5, stride 3), split-K over ic ----
  {
    const int oc  = tid & 127;
    const int grp = tid >> 7;          // 0: ic 0..10, 1: ic 11..21
    const int ic0 = grp ? 11 : 0;
    float acc[9];
    #pragma unroll
    for (int p = 0; p < 9; p++) acc[p] = 0.0f;
    const float* w = wc1 + (long)oc * (NL*25);
    for (int ic = ic0; ic < ic0 + 11; ic++) {
      const float* f = &feat[ic*PLANE];
      const float* wp = w + ic*25;
      float wr[25];
      #pragma unroll
      for (int i = 0; i < 25; i++) wr[i] = wp[i];
      #pragma unroll
      for (int ox = 0; ox < 3; ox++)
        #pragma unroll
        for (int kx = 0; kx < 5; kx++) {
          const float* frow = f + (ox*3 + kx)*OWW;
          #pragma unroll
          for (int oy = 0; oy < 3; oy++)
            #pragma unroll
            for (int ky = 0; ky < 5; ky++)
              acc[ox*3+oy] = fmaf(frow[oy*3 + ky], wr[kx*5 + ky], acc[ox*3+oy]);
        }
    }
    if (grp) {
      #pragma unroll
      for (int p = 0; p < 9; p++) p1[oc*9 + p] = acc[p];
    }
    __syncthreads();
    if (!grp) {
      float bias = bc1[oc];
      #pragma unroll
      for (int p = 0; p < 9; p++)
        h1[oc*9 + p] = fmaxf(acc[p] + p1[oc*9 + p] + bias, 0.0f);
    }
    __syncthreads();
  }

  // ---- conv2: 128ch 3x3 -> 128 (3x3 valid), split-K over ic halves ----
  {
    const int oc  = tid & 127;
    const int grp = tid >> 7;          // k range grp*576 .. +576  (k = ic*9+p)
    float acc = 0.0f;
    const float4* wq = reinterpret_cast<const float4*>(wc2 + (long)oc*1152 + grp*576);
    #pragma unroll 4
    for (int q = 0; q < 144; q++) {
      float4 u = wq[q];
      int k = grp*576 + q*4;
      acc = fmaf(h1[k+0], u.x, acc);
      acc = fmaf(h1[k+1], u.y, acc);
      acc = fmaf(h1[k+2], u.z, acc);
      acc = fmaf(h1[k+3], u.w, acc);
    }
    if (grp) p1[oc] = acc;
    __syncthreads();
    if (!grp) h2[oc] = fmaxf(acc + p1[oc] + bc2[oc], 0.0f);
    __syncthreads();
  }

  // ---- fc: hid[256:512] = relu(h2 @ w_fc + b_fc) ----
  {
    float acc = bfc[tid];
    for (int k = 0; k < CH; k++)
      acc = fmaf(h2[k], wfc[k*256 + tid], acc);
    hid[256 + tid] = fmaxf(acc, 0.0f);
  }
  __syncthreads();

  // ---- heads: 20 outputs, 8 lanes each, shuffle-reduce ----
  if (tid < 160) {
    int o = tid >> 3, s = tid & 7;
    const float* W; int n, col;
    if (o < 9)       { W = wa0; n = 9;  col = o; }
    else if (o < 19) { W = wa1; n = 10; col = o - 9; }
    else             { W = wv;  n = 1;  col = 0; }
    float acc = 0.0f;
    #pragma unroll 8
    for (int j = 0; j < 64; j++) {
      int k = s*64 + j;
      acc = fmaf(hid[k], W[k*n + col], acc);
    }
    acc += __shfl_xor(acc, 1);
    acc += __shfl_xor(acc, 2);
    acc += __shfl_xor(acc, 4);
    if (s == 0) {
      float bias = (o < 9) ? ba0[o] : (o < 19 ? ba1[o-9] : bv[0]);
      float r = acc + bias;
      long off;
      if (o < 9)       off = (long)b*9 + o;
      else if (o < 19) off = (long)B_TOT*9  + (long)b*10 + (o - 9);
      else             off = (long)B_TOT*19 + b;
      out[off] = r;
    }
  }

  // ---- hidden out ----
  #pragma unroll
  for (int i = tid; i < HIDDEN; i += 256)
    out[(long)B_TOT*20 + (long)b*HIDDEN + i] = hid[i];
}

extern "C" void kernel_launch(void* const* d_in, const int* in_sizes, int n_in,
                              void* d_out, int out_size, void* d_ws, size_t ws_size,
                              hipStream_t stream) {
  const int* obs      = (const int*)d_in[0];
  const float* maxvec = (const float*)d_in[1];
  const float* wc1    = (const float*)d_in[2];
  const float* bc1    = (const float*)d_in[3];
  const float* wc2    = (const float*)d_in[4];
  const float* bc2    = (const float*)d_in[5];
  const float* wfc    = (const float*)d_in[6];
  const float* bfc    = (const float*)d_in[7];
  const float* wself  = (const float*)d_in[8];
  const float* bself  = (const float*)d_in[9];
  const float* wa0    = (const float*)d_in[10];
  const float* ba0    = (const float*)d_in[11];
  const float* wa1    = (const float*)d_in[12];
  const float* ba1    = (const float*)d_in[13];
  const float* wv     = (const float*)d_in[14];
  const float* bv     = (const float*)d_in[15];
  float* out          = (float*)d_out;

  policy_fwd<<<dim3(B_TOT), dim3(256), 0, stream>>>(
      obs, maxvec, wc1, bc1, wc2, bc2, wfc, bfc, wself, bself,
      wa0, ba0, wa1, ba1, wv, bv, out);
}

// Round 3
// 637.696 us; speedup vs baseline: 5.2391x; 5.2391x over previous
//
#include <hip/hip_runtime.h>
#include <hip/hip_bf16.h>

typedef unsigned int  uint;
typedef unsigned short ushort;

#define B_TOT 32768
#define NL    22
#define NS1   4
#define NS2   8

// ws layout (bytes)
#define H1_OFF  0                 // bf16 [B_TOT][1152] = 75,497,472 B
#define W2P_OFF 75497472          // uint [576][128]    = 294,912 B
#define W1T_OFF 75792384          // float [550][128]   = 281,600 B
// total ws need: 76,073,984 B

// ---------- prologue: weight repack (coalesced layouts) ----------
extern "C" __global__ __launch_bounds__(256)
void k_prep(const float* __restrict__ wc2, const float* __restrict__ wc1,
            uint* __restrict__ w2p, float* __restrict__ w1t)
{
  int idx = blockIdx.x * 256 + threadIdx.x;
  if (idx < 73728) {                      // w2p[k2*128+oc] = pack(wc2[oc][2k2], wc2[oc][2k2+1])
    int oc = idx & 127, k2 = idx >> 7;
    __hip_bfloat16 ha = __float2bfloat16(wc2[oc*1152 + 2*k2]);
    __hip_bfloat16 hb = __float2bfloat16(wc2[oc*1152 + 2*k2 + 1]);
    uint ua = *(const ushort*)&ha, ub = *(const ushort*)&hb;
    w2p[idx] = ua | (ub << 16);
  } else if (idx < 73728 + 70400) {       // w1t[r*128+oc] = wc1[oc][r], r = a*25+kx*5+ky
    int j = idx - 73728;
    int oc = j & 127, r = j >> 7;
    w1t[j] = wc1[oc*550 + r];
  }
}

// ---------- kernel 1: scatter/dedup + sparse conv1 + self head ----------
extern "C" __global__ __launch_bounds__(256)
void k_encode(const int* __restrict__ obs, const float* __restrict__ maxvec,
              const float* __restrict__ w1t, const float* __restrict__ bc1,
              const float* __restrict__ wself, const float* __restrict__ bself,
              float* __restrict__ out, uint* __restrict__ h1g)
{
  __shared__ int    toks[NS1*600];
  __shared__ int    cell[NS1*200];
  __shared__ uint   pk[NS1*200];
  __shared__ uint   slist[NS1][200];
  __shared__ int    cnt[NS1];
  __shared__ float  maxv[NL];
  __shared__ float  p1[1152];
  __shared__ ushort h1su[1152];

  const int tid = threadIdx.x;
  const int b0  = blockIdx.x * NS1;

  const int* op = obs + (long)b0 * 600;
  for (int i = tid; i < NS1*600; i += 256) toks[i] = op[i];
  if (tid < NL)  maxv[tid] = maxvec[tid];
  if (tid < NS1) cnt[tid] = 0;
  __syncthreads();

  // decode tokens (255 -> 0 per component, as reference)
  for (int i = tid; i < NS1*200; i += 256) {
    int s = i / 200, m = i - s*200;
    int base = s*600 + m*3;
    int c = toks[base], a = toks[base+1], v = toks[base+2];
    c = (c==255) ? 0 : c;  a = (a==255) ? 0 : a;  v = (v==255) ? 0 : v;
    int x = (c >> 4) & 15, y = c & 15;
    bool valid = (x < 11) && (y < 11) && (a < NL);
    cell[i] = valid ? ((a<<8)|(x<<4)|y) : -1;
    pk[i]   = ((uint)a<<16)|((uint)x<<12)|((uint)y<<8)|(uint)v;
  }
  __syncthreads();

  // last-write-wins dedup + compact (sum over distinct cells is order-free)
  for (int i = tid; i < NS1*200; i += 256) {
    int cid = cell[i];
    if (cid >= 0) {
      int s = i / 200, m = i - s*200;
      const int* cs = &cell[s*200];
      bool dead = false;
      for (int m2 = m+1; m2 < 200; ++m2) dead |= (cs[m2] == cid);
      if (!dead) slist[s][atomicAdd(&cnt[s],1)] = pk[i];
    }
  }
  __syncthreads();

  for (int s = 0; s < NS1; ++s) {
    const int n = cnt[s];
    const int b = b0 + s;

    // self head -> out hidden[:, 0:256]
    {
      float acc = bself[tid];
      for (int t = 0; t < n; ++t) {
        uint u = slist[s][t];
        int x = (u>>12)&15, y = (u>>8)&15;
        if (x == 5 && y == 5) {
          int a = u >> 16;
          float fv = (float)(u & 255) / maxv[a];
          acc = fmaf(fv, wself[a*256 + tid], acc);
        }
      }
      out[(long)B_TOT*20 + (long)b*512 + tid] = fmaxf(acc, 0.f);
    }

    // sparse conv1: each token hits <=4 of the 9 output positions
    const int oc = tid & 127, half = tid >> 7;
    float acc[9];
    #pragma unroll
    for (int p = 0; p < 9; ++p) acc[p] = 0.f;
    for (int t = half; t < n; t += 2) {
      uint u = slist[s][t];
      int a = u >> 16, x = (u>>12)&15, y = (u>>8)&15;
      float fv = (float)(u & 255) / maxv[a];
      #pragma unroll
      for (int ox = 0; ox < 3; ++ox) {
        int kx = x - 3*ox;
        if (kx < 0 || kx > 4) continue;
        #pragma unroll
        for (int oy = 0; oy < 3; ++oy) {
          int ky = y - 3*oy;
          if (ky < 0 || ky > 4) continue;
          float w = w1t[(a*25 + kx*5 + ky)*128 + oc];   // coalesced over oc
          acc[ox*3+oy] = fmaf(fv, w, acc[ox*3+oy]);
        }
      }
    }
    if (half) {
      #pragma unroll
      for (int p = 0; p < 9; ++p) p1[oc*9+p] = acc[p];
    }
    __syncthreads();
    if (!half) {
      float bias = bc1[oc];
      #pragma unroll
      for (int p = 0; p < 9; ++p) {
        float r = fmaxf(acc[p] + p1[oc*9+p] + bias, 0.f);
        __hip_bfloat16 h = __float2bfloat16(r);
        h1su[oc*9+p] = *(const ushort*)&h;
      }
    }
    __syncthreads();
    const uint* h1sv = (const uint*)h1su;
    for (int i = tid; i < 576; i += 256)
      h1g[(long)b*576 + i] = h1sv[i];
    __syncthreads();
  }
}

// ---------- kernel 2: conv2 + fc + heads ----------
extern "C" __global__ __launch_bounds__(256)
void k_mlp(const uint* __restrict__ h1g, const uint* __restrict__ w2p,
           const float* __restrict__ bc2, const float* __restrict__ wfc,
           const float* __restrict__ bfc,
           const float* __restrict__ wa0, const float* __restrict__ ba0,
           const float* __restrict__ wa1, const float* __restrict__ ba1,
           const float* __restrict__ wv,  const float* __restrict__ bv,
           float* __restrict__ out)
{
  __shared__ float h1t[NS2*1152];   // 36.9 KB
  __shared__ float pbuf[NS2*128];
  __shared__ float h2[NS2*128];
  __shared__ float cf[NS2*256];
  __shared__ float sf[NS2*256];

  const int tid = threadIdx.x;
  const int b0  = blockIdx.x * NS2;
  const long HID0 = (long)B_TOT * 20;

  // load h1 tile (bf16 -> fp32 once)
  const uint* hp = h1g + (long)b0 * 576;
  for (int i = tid; i < NS2*576; i += 256) {
    uint u = hp[i];
    h1t[2*i]   = __uint_as_float(u << 16);
    h1t[2*i+1] = __uint_as_float(u & 0xffff0000u);
  }
  // self_feat tile (written by k_encode)
  for (int i = tid; i < NS2*256; i += 256) {
    int s = i >> 8, j = i & 255;
    sf[i] = out[HID0 + (long)(b0+s)*512 + j];
  }
  __syncthreads();

  // conv2 as K=1152 GEMV batch, weights coalesced bf16 pairs, samples inner
  {
    const int oc = tid & 127, half = tid >> 7;
    float acc[NS2];
    #pragma unroll
    for (int s = 0; s < NS2; ++s) acc[s] = 0.f;
    const uint* wp = w2p + half*288*128 + oc;
    #pragma unroll 2
    for (int j2 = 0; j2 < 288; ++j2) {
      uint u = wp[j2*128];
      float w0 = __uint_as_float(u << 16);
      float w1 = __uint_as_float(u & 0xffff0000u);
      int k = (half*288 + j2) * 2;
      #pragma unroll
      for (int s = 0; s < NS2; ++s) {
        acc[s] = fmaf(h1t[s*1152+k],   w0, acc[s]);
        acc[s] = fmaf(h1t[s*1152+k+1], w1, acc[s]);
      }
    }
    if (half) {
      #pragma unroll
      for (int s = 0; s < NS2; ++s) pbuf[s*128+oc] = acc[s];
    }
    __syncthreads();
    if (!half) {
      float bias = bc2[oc];
      #pragma unroll
      for (int s = 0; s < NS2; ++s)
        h2[s*128+oc] = fmaxf(acc[s] + pbuf[s*128+oc] + bias, 0.f);
    }
    __syncthreads();
  }

  // fc: cnn_feat = relu(h2 @ wfc + bfc), wfc already [k][j] coalesced
  {
    float acc[NS2];
    #pragma unroll
    for (int s = 0; s < NS2; ++s) acc[s] = 0.f;
    for (int k = 0; k < 128; ++k) {
      float w = wfc[k*256 + tid];
      #pragma unroll
      for (int s = 0; s < NS2; ++s) acc[s] = fmaf(h2[s*128+k], w, acc[s]);
    }
    float bias = bfc[tid];
    #pragma unroll
    for (int s = 0; s < NS2; ++s) {
      float r = fmaxf(acc[s] + bias, 0.f);
      cf[s*256+tid] = r;
      out[HID0 + (long)(b0+s)*512 + 256 + tid] = r;
    }
  }
  __syncthreads();

  // heads: 20 outputs x NS2 samples, one thread each, K=512
  if (tid < 20*NS2) {
    int s = tid / 20, o = tid % 20;
    const float* W; int nn, col; float bias;
    if (o < 9)       { W = wa0; nn = 9;  col = o;     bias = ba0[o];   }
    else if (o < 19) { W = wa1; nn = 10; col = o - 9; bias = ba1[o-9]; }
    else             { W = wv;  nn = 1;  col = 0;     bias = bv[0];    }
    float acc = bias;
    for (int k = 0; k < 256; ++k) acc = fmaf(sf[s*256+k], W[k*nn + col], acc);
    for (int k = 0; k < 256; ++k) acc = fmaf(cf[s*256+k], W[(256+k)*nn + col], acc);
    int b = b0 + s;
    long off;
    if (o < 9)       off = (long)b*9 + o;
    else if (o < 19) off = (long)B_TOT*9 + (long)b*10 + (o-9);
    else             off = (long)B_TOT*19 + b;
    out[off] = acc;
  }
}

extern "C" void kernel_launch(void* const* d_in, const int* in_sizes, int n_in,
                              void* d_out, int out_size, void* d_ws, size_t ws_size,
                              hipStream_t stream) {
  const int* obs      = (const int*)d_in[0];
  const float* maxvec = (const float*)d_in[1];
  const float* wc1    = (const float*)d_in[2];
  const float* bc1    = (const float*)d_in[3];
  const float* wc2    = (const float*)d_in[4];
  const float* bc2    = (const float*)d_in[5];
  const float* wfc    = (const float*)d_in[6];
  const float* bfc    = (const float*)d_in[7];
  const float* wself  = (const float*)d_in[8];
  const float* bself  = (const float*)d_in[9];
  const float* wa0    = (const float*)d_in[10];
  const float* ba0    = (const float*)d_in[11];
  const float* wa1    = (const float*)d_in[12];
  const float* ba1    = (const float*)d_in[13];
  const float* wv     = (const float*)d_in[14];
  const float* bv     = (const float*)d_in[15];
  float* out          = (float*)d_out;

  char* ws = (char*)d_ws;
  uint*  h1g = (uint*)(ws + H1_OFF);
  uint*  w2p = (uint*)(ws + W2P_OFF);
  float* w1t = (float*)(ws + W1T_OFF);

  k_prep  <<<dim3(563),          dim3(256), 0, stream>>>(wc2, wc1, w2p, w1t);
  k_encode<<<dim3(B_TOT/NS1),    dim3(256), 0, stream>>>(obs, maxvec, w1t, bc1,
                                                         wself, bself, out, h1g);
  k_mlp   <<<dim3(B_TOT/NS2),    dim3(256), 0, stream>>>(h1g, w2p, bc2, wfc, bfc,
                                                         wa0, ba0, wa1, ba1, wv, bv, out);
}

// Round 4
// 189.613 us; speedup vs baseline: 17.6200x; 3.3632x over previous
//
#include <hip/hip_runtime.h>
#include <hip/hip_bf16.h>

typedef unsigned int uint;
typedef unsigned short ushort;
typedef unsigned long long ull;
typedef __attribute__((ext_vector_type(8))) short short8;
typedef __attribute__((ext_vector_type(4))) float float4_;

#define B_TOT 32768
#define NL    22
#define HID0  ((long)B_TOT * 20)

// ws layout (bytes), all 16B-aligned
#define W2F_OFF  0          // bf16 frag-packed conv2 W: 36*8*64*8*2   = 294,912
#define WFCF_OFF 294912     // bf16 frag-packed fc W:    4*16*64*8*2   = 65,536
#define W1T_OFF  360448     // f32 conv1 W transposed:   550*128*4     = 281,600
#define H1_OFF   642048     // bf16 h1: 32768*1152*2                   = 75,497,472
// total: 76,139,520 B

__device__ __forceinline__ ushort f2bf(float v) {
  uint x = __float_as_uint(v);
  x += 0x7fffu + ((x >> 16) & 1u);        // RNE (no NaN inputs here)
  return (ushort)(x >> 16);
}

// ---------------- prologue: weight repack ----------------
extern "C" __global__ __launch_bounds__(256)
void k_prep(const float* __restrict__ wc1, const float* __restrict__ wc2,
            const float* __restrict__ wfc,
            ushort* __restrict__ w2f, ushort* __restrict__ wfcf,
            float* __restrict__ w1t)
{
  int i = blockIdx.x * 256 + threadIdx.x;
  if (i < 18432) {
    // conv2 B-frags: entry (ks,cg,l) = B[k=ks*32+(l>>4)*8+j][col=cg*16+(l&15)]
    //              = wc2[col][k]  (wc2 is [oc][1152] row-major)
    int l = i & 63, cg = (i >> 6) & 7, ks = i >> 9;
    int col = cg * 16 + (l & 15);
    int kb  = ks * 32 + (l >> 4) * 8;
    ushort t[8];
    #pragma unroll
    for (int j = 0; j < 8; ++j) t[j] = f2bf(wc2[col * 1152 + kb + j]);
    uint4 o;
    o.x = (uint)t[0] | ((uint)t[1] << 16);
    o.y = (uint)t[2] | ((uint)t[3] << 16);
    o.z = (uint)t[4] | ((uint)t[5] << 16);
    o.w = (uint)t[6] | ((uint)t[7] << 16);
    ((uint4*)w2f)[i] = o;
  } else if (i < 18432 + 4096) {
    // fc B-frags: wfc is [k=128][col=256] row-major
    int i2 = i - 18432;
    int l = i2 & 63, cg = (i2 >> 6) & 15, ks = i2 >> 10;
    int col = cg * 16 + (l & 15);
    int kb  = ks * 32 + (l >> 4) * 8;
    ushort t[8];
    #pragma unroll
    for (int j = 0; j < 8; ++j) t[j] = f2bf(wfc[(kb + j) * 256 + col]);
    uint4 o;
    o.x = (uint)t[0] | ((uint)t[1] << 16);
    o.y = (uint)t[2] | ((uint)t[3] << 16);
    o.z = (uint)t[4] | ((uint)t[5] << 16);
    o.w = (uint)t[6] | ((uint)t[7] << 16);
    ((uint4*)wfcf)[i2] = o;
  } else if (i < 18432 + 4096 + 70400) {
    // w1t[r*128+oc] = wc1[oc][r], r = a*25+kx*5+ky
    int j = i - 18432 - 4096;
    int oc = j & 127, r = j >> 7;
    w1t[j] = wc1[oc * 550 + r];
  }
}

// ---------------- kernel 1: tokens -> sparse conv1 + self head ----------------
// 1 wave per sample, 4 samples per block.
extern "C" __global__ __launch_bounds__(256)
void k_encode(const int* __restrict__ obs, const float* __restrict__ maxvec,
              const float* __restrict__ w1t, const float* __restrict__ bc1,
              const float* __restrict__ wself, const float* __restrict__ bself,
              float* __restrict__ out, ushort* __restrict__ h1g)
{
  __shared__ uint   klist[4][64];
  __shared__ ushort h1su[4][1152];
  __shared__ float  maxv[NL];

  const int tid = threadIdx.x, lane = tid & 63, w = tid >> 6;
  const long b = (long)blockIdx.x * 4 + w;
  if (tid < NL) maxv[tid] = maxvec[tid];

  // ---- ordered compaction of valid tokens (preserves m order) ----
  const int* ob = obs + b * 600;
  int cnt = 0;
  #pragma unroll
  for (int r = 0; r < 4; ++r) {
    int m = r * 64 + lane;
    bool valid = false; uint pk = 0;
    if (m < 200) {
      int c = ob[m*3], a = ob[m*3+1], v = ob[m*3+2];
      c = (c == 255) ? 0 : c;  a = (a == 255) ? 0 : a;  v = (v == 255) ? 0 : v;
      int x = (c >> 4) & 15, y = c & 15;
      valid = (x < 11) && (y < 11) && (a < NL);
      pk = ((uint)a << 16) | ((uint)x << 12) | ((uint)y << 8) | (uint)v;
    }
    ull bal = __ballot(valid);
    if (valid) {
      int pos = cnt + __popcll(bal & ((1ull << lane) - 1ull));
      if (pos < 64) klist[w][pos] = pk;
    }
    cnt += __popcll(bal);
  }
  if (cnt > 64) cnt = 64;

  // ---- dedup: last write wins (token dead if any later token shares cell) ----
  uint u = 0; bool alive = false;
  if (lane < cnt) {
    u = klist[w][lane];
    alive = true;
    uint cell = u >> 8;
    for (int t2 = lane + 1; t2 < cnt; ++t2)
      if ((klist[w][t2] >> 8) == cell) { alive = false; break; }
  }
  ull bal2 = __ballot(alive);
  const int n2 = __popcll(bal2);
  if (alive) {
    int pos = __popcll(bal2 & ((1ull << lane) - 1ull));
    klist[w][pos] = u;
  }
  __syncthreads();   // maxv visibility (klist is wave-local)

  // ---- sparse conv1 (2 oc per lane) + self head (4 j per lane) ----
  float a0[9] = {0,0,0,0,0,0,0,0,0}, a1[9] = {0,0,0,0,0,0,0,0,0};
  float s0 = 0.f, s1 = 0.f, s2 = 0.f, s3 = 0.f;
  for (int t = 0; t < n2; ++t) {
    uint tk = klist[w][t];                       // wave-uniform broadcast
    int a = tk >> 16, x = (tk >> 12) & 15, y = (tk >> 8) & 15;
    float fv = (float)(tk & 255u) / maxv[a];
    if (x == 5 && y == 5) {
      s0 = fmaf(fv, wself[a*256 + lane      ], s0);
      s1 = fmaf(fv, wself[a*256 + 64  + lane], s1);
      s2 = fmaf(fv, wself[a*256 + 128 + lane], s2);
      s3 = fmaf(fv, wself[a*256 + 192 + lane], s3);
    }
    #pragma unroll
    for (int ox = 0; ox < 3; ++ox) {
      int kx = x - 3 * ox;
      if ((unsigned)kx > 4u) continue;
      #pragma unroll
      for (int oy = 0; oy < 3; ++oy) {
        int ky = y - 3 * oy;
        if ((unsigned)ky > 4u) continue;
        const float* wr = w1t + (a*25 + kx*5 + ky) * 128;
        a0[ox*3+oy] = fmaf(fv, wr[lane],      a0[ox*3+oy]);
        a1[ox*3+oy] = fmaf(fv, wr[64 + lane], a1[ox*3+oy]);
      }
    }
  }

  // self_feat -> out hidden[:, 0:256] (fp32)
  out[HID0 + b*512 + lane      ] = fmaxf(s0 + bself[lane      ], 0.f);
  out[HID0 + b*512 + 64  + lane] = fmaxf(s1 + bself[64  + lane], 0.f);
  out[HID0 + b*512 + 128 + lane] = fmaxf(s2 + bself[128 + lane], 0.f);
  out[HID0 + b*512 + 192 + lane] = fmaxf(s3 + bself[192 + lane], 0.f);

  // h1 -> bf16, k-order = oc*9 + (ox*3+oy)
  float bb0 = bc1[lane], bb1 = bc1[64 + lane];
  #pragma unroll
  for (int p = 0; p < 9; ++p) {
    h1su[w][lane*9 + p]        = f2bf(fmaxf(a0[p] + bb0, 0.f));
    h1su[w][(64 + lane)*9 + p] = f2bf(fmaxf(a1[p] + bb1, 0.f));
  }
  const uint* sv = (const uint*)&h1su[w][0];
  uint* dst = (uint*)(h1g + b * 1152);
  #pragma unroll
  for (int i = lane; i < 576; i += 64) dst[i] = sv[i];
}

// ---------------- kernel 2: conv2 + fc via MFMA ----------------
// M-tile 64 (1 m-frag per wave), N=128 then N=256, K staged in LDS.
extern "C" __global__ __launch_bounds__(256)
void k_mlp(const ushort* __restrict__ h1g, const ushort* __restrict__ w2f,
           const float* __restrict__ bc2, const ushort* __restrict__ wfcf,
           const float* __restrict__ bfc, float* __restrict__ out)
{
  __shared__ short  Abuf[2][4][64][8];   // [buf][kchunk][row][8 bf16] = 16 KB
  __shared__ ushort h2A[16][64][8];      // [kchunk][row][8 bf16]      = 16 KB

  const int tid = threadIdx.x, lane = tid & 63, w = tid >> 6;
  const int lo = lane & 15, hi = lane >> 4;
  const int b0 = blockIdx.x * 64;

  const short8* w2fv  = (const short8*)w2f;
  const short8* wfcfv = (const short8*)wfcf;

  // conv2 accumulators, bias preloaded (C layout: row=hi*4+q, col=cg*16+lo)
  float4_ acc[8];
  #pragma unroll
  for (int cg = 0; cg < 8; ++cg) {
    float bv_ = bc2[cg*16 + lo];
    float4_ t = {bv_, bv_, bv_, bv_};
    acc[cg] = t;
  }

  // thread (w,lane) stages A chunk c=w, row=lane
  const ushort* asrc = h1g + (long)(b0 + lane) * 1152 + w * 8;
  uint4 rA = *(const uint4*)asrc;

  for (int t = 0; t < 36; ++t) {
    const int cur = t & 1;
    *(uint4*)&Abuf[cur][w][lane][0] = rA;
    if (t + 1 < 36) rA = *(const uint4*)(asrc + (t + 1) * 32);
    __syncthreads();
    short8 af = *(const short8*)&Abuf[cur][hi][w*16 + lo][0];
    #pragma unroll
    for (int cg = 0; cg < 8; ++cg) {
      short8 bf = w2fv[(t*8 + cg)*64 + lane];
      acc[cg] = __builtin_amdgcn_mfma_f32_16x16x32_bf16(af, bf, acc[cg], 0, 0, 0);
    }
    // single barrier per step is safe: next write targets the other buffer
  }
  __syncthreads();

  // h2 = relu(acc) -> LDS bf16 in A-frag layout
  #pragma unroll
  for (int cg = 0; cg < 8; ++cg) {
    int col = cg*16 + lo;
    #pragma unroll
    for (int q = 0; q < 4; ++q) {
      int R = w*16 + hi*4 + q;
      h2A[col >> 3][R][col & 7] = f2bf(fmaxf(acc[cg][q], 0.f));
    }
  }
  __syncthreads();

  // fc: [64][128] @ [128][256]
  float4_ acc2[16];
  #pragma unroll
  for (int cg = 0; cg < 16; ++cg) {
    float bv_ = bfc[cg*16 + lo];
    float4_ t = {bv_, bv_, bv_, bv_};
    acc2[cg] = t;
  }
  #pragma unroll
  for (int ks = 0; ks < 4; ++ks) {
    short8 af = *(const short8*)&h2A[ks*4 + hi][w*16 + lo][0];
    #pragma unroll
    for (int cg = 0; cg < 16; ++cg) {
      short8 bf = wfcfv[(ks*16 + cg)*64 + lane];
      acc2[cg] = __builtin_amdgcn_mfma_f32_16x16x32_bf16(af, bf, acc2[cg], 0, 0, 0);
    }
  }

  // cnn_feat -> out hidden[:, 256:512] (fp32)
  #pragma unroll
  for (int cg = 0; cg < 16; ++cg) {
    int col = cg*16 + lo;
    #pragma unroll
    for (int q = 0; q < 4; ++q) {
      int R = w*16 + hi*4 + q;
      out[HID0 + (long)(b0 + R)*512 + 256 + col] = fmaxf(acc2[cg][q], 0.f);
    }
  }
}

// ---------------- kernel 3: heads ----------------
#define HS 8
extern "C" __global__ __launch_bounds__(256)
void k_heads(const float* __restrict__ wa0, const float* __restrict__ ba0,
             const float* __restrict__ wa1, const float* __restrict__ ba1,
             const float* __restrict__ wv,  const float* __restrict__ bv,
             float* __restrict__ out)
{
  __shared__ float hid[HS][520];      // padded stride: no bank conflicts
  __shared__ float W[512 * 20];       // [k][o]
  const int tid = threadIdx.x;
  const long b0 = (long)blockIdx.x * HS;

  for (int i = tid; i < 512 * 20; i += 256) {
    int k = i / 20, o = i - k * 20;
    W[i] = (o < 9) ? wa0[k*9 + o] : (o < 19 ? wa1[k*10 + (o - 9)] : wv[k]);
  }
  for (int i = tid; i < HS * 512; i += 256) {
    int s = i >> 9, k = i & 511;
    hid[s][k] = out[HID0 + (b0 + s)*512 + k];
  }
  __syncthreads();

  if (tid < HS * 20) {
    int s = tid / 20, o = tid - s * 20;
    float acc = (o < 9) ? ba0[o] : (o < 19 ? ba1[o - 9] : bv[0]);
    const float* hs = hid[s];
    for (int k = 0; k < 512; ++k)
      acc = fmaf(hs[k], W[k*20 + o], acc);
    long bb = b0 + s;
    long off = (o < 9)  ? bb*9 + o
             : (o < 19) ? (long)B_TOT*9 + bb*10 + (o - 9)
             :            (long)B_TOT*19 + bb;
    out[off] = acc;
  }
}

extern "C" void kernel_launch(void* const* d_in, const int* in_sizes, int n_in,
                              void* d_out, int out_size, void* d_ws, size_t ws_size,
                              hipStream_t stream) {
  const int* obs      = (const int*)d_in[0];
  const float* maxvec = (const float*)d_in[1];
  const float* wc1    = (const float*)d_in[2];
  const float* bc1    = (const float*)d_in[3];
  const float* wc2    = (const float*)d_in[4];
  const float* bc2    = (const float*)d_in[5];
  const float* wfc    = (const float*)d_in[6];
  const float* bfc    = (const float*)d_in[7];
  const float* wself  = (const float*)d_in[8];
  const float* bself  = (const float*)d_in[9];
  const float* wa0    = (const float*)d_in[10];
  const float* ba0    = (const float*)d_in[11];
  const float* wa1    = (const float*)d_in[12];
  const float* ba1    = (const float*)d_in[13];
  const float* wv     = (const float*)d_in[14];
  const float* bv     = (const float*)d_in[15];
  float* out          = (float*)d_out;

  char* ws = (char*)d_ws;
  ushort* w2f  = (ushort*)(ws + W2F_OFF);
  ushort* wfcf = (ushort*)(ws + WFCF_OFF);
  float*  w1t  = (float*)(ws + W1T_OFF);
  ushort* h1g  = (ushort*)(ws + H1_OFF);

  k_prep  <<<dim3(363),        dim3(256), 0, stream>>>(wc1, wc2, wfc, w2f, wfcf, w1t);
  k_encode<<<dim3(B_TOT/4),    dim3(256), 0, stream>>>(obs, maxvec, w1t, bc1,
                                                       wself, bself, out, h1g);
  k_mlp   <<<dim3(B_TOT/64),   dim3(256), 0, stream>>>(h1g, w2f, bc2, wfcf, bfc, out);
  k_heads <<<dim3(B_TOT/HS),   dim3(256), 0, stream>>>(wa0, ba0, wa1, ba1, wv, bv, out);
}

// Round 5
// 136.564 us; speedup vs baseline: 24.4646x; 1.3885x over previous
//
#include <hip/hip_runtime.h>
#include <hip/hip_bf16.h>

typedef unsigned int uint;
typedef unsigned short ushort;
typedef unsigned long long ull;
typedef __attribute__((ext_vector_type(8))) short short8;
typedef __attribute__((ext_vector_type(4))) float float4_;

#define B_TOT 32768
#define NL    22
#define HID0  ((long)B_TOT * 20)

// ws layout (bytes), 16B aligned
#define W2F_OFF  0          // conv2 B-frags bf16: 36*8*64*16B  = 294,912
#define WFCF_OFF 294912     // fc    B-frags bf16: 4*16*64*16B  = 65,536
#define WHF_OFF  360448     // heads B-frags bf16: 16*2*64*16B  = 32,768
#define W1T_OFF  393216     // conv1 W^T f32: 550*128*4          = 281,600
#define H1_OFF   674816     // h1 tiled bf16: 512*36*64*32*2     = 75,497,472
// total 76,172,288

__device__ __forceinline__ ushort f2bf(float v) {
  uint x = __float_as_uint(v);
  x += 0x7fffu + ((x >> 16) & 1u);
  return (ushort)(x >> 16);
}

// ---------------- prologue: weight repack ----------------
extern "C" __global__ __launch_bounds__(256)
void k_prep(const float* __restrict__ wc1, const float* __restrict__ wc2,
            const float* __restrict__ wfc,
            const float* __restrict__ wa0, const float* __restrict__ wa1,
            const float* __restrict__ wv,
            ushort* __restrict__ w2f, ushort* __restrict__ wfcf,
            ushort* __restrict__ whf, float* __restrict__ w1t)
{
  int i = blockIdx.x * 256 + threadIdx.x;
  if (i < 18432) {                       // conv2: B[k][col] = wc2[col][k]
    int l = i & 63, cg = (i >> 6) & 7, ks = i >> 9;
    int col = cg * 16 + (l & 15), kb = ks * 32 + (l >> 4) * 8;
    ushort t[8];
    #pragma unroll
    for (int j = 0; j < 8; ++j) t[j] = f2bf(wc2[col * 1152 + kb + j]);
    uint4 o = { (uint)t[0]|((uint)t[1]<<16), (uint)t[2]|((uint)t[3]<<16),
                (uint)t[4]|((uint)t[5]<<16), (uint)t[6]|((uint)t[7]<<16) };
    ((uint4*)w2f)[i] = o;
  } else if (i < 22528) {                // fc: B[k][col] = wfc[k][col]
    int i2 = i - 18432;
    int l = i2 & 63, cg = (i2 >> 6) & 15, ks = i2 >> 10;
    int col = cg * 16 + (l & 15), kb = ks * 32 + (l >> 4) * 8;
    ushort t[8];
    #pragma unroll
    for (int j = 0; j < 8; ++j) t[j] = f2bf(wfc[(kb + j) * 256 + col]);
    uint4 o = { (uint)t[0]|((uint)t[1]<<16), (uint)t[2]|((uint)t[3]<<16),
                (uint)t[4]|((uint)t[5]<<16), (uint)t[6]|((uint)t[7]<<16) };
    ((uint4*)wfcf)[i2] = o;
  } else if (i < 24576) {                // heads: cols 0..8 wa0, 9..18 wa1, 19 wv, 20..31 zero
    int i2 = i - 22528;
    int l = i2 & 63, cg = (i2 >> 6) & 1, ks = i2 >> 7;
    int col = cg * 16 + (l & 15), kb = ks * 32 + (l >> 4) * 8;
    ushort t[8];
    #pragma unroll
    for (int j = 0; j < 8; ++j) {
      int k = kb + j;
      float v = (col < 9)  ? wa0[k*9 + col]
              : (col < 19) ? wa1[k*10 + (col - 9)]
              : (col == 19) ? wv[k] : 0.f;
      t[j] = f2bf(v);
    }
    uint4 o = { (uint)t[0]|((uint)t[1]<<16), (uint)t[2]|((uint)t[3]<<16),
                (uint)t[4]|((uint)t[5]<<16), (uint)t[6]|((uint)t[7]<<16) };
    ((uint4*)whf)[i2] = o;
  } else if (i < 24576 + 70400) {        // w1t[r*128+oc] = wc1[oc][r]
    int j = i - 24576;
    int oc = j & 127, r = j >> 7;
    w1t[j] = wc1[oc * 550 + r];
  }
}

// ---------------- kernel 1: tokens -> sparse conv1 + self head ----------------
extern "C" __global__ __launch_bounds__(256)
void k_encode(const int* __restrict__ obs, const float* __restrict__ maxvec,
              const float* __restrict__ w1t, const float* __restrict__ bc1,
              const float* __restrict__ wself, const float* __restrict__ bself,
              float* __restrict__ out, ushort* __restrict__ h1g)
{
  __shared__ uint4  tksf[600];          // 4 samples x 150 uint4 (coalesced stage)
  __shared__ uint   klist[4][64];
  __shared__ ushort h1su[4][1152];
  __shared__ float  rmaxv[NL];

  const int tid = threadIdx.x, lane = tid & 63, w = tid >> 6;
  const long b = (long)blockIdx.x * 4 + w;

  // coalesced obs stage: 600 uint4 across the block
  const uint4* o4 = (const uint4*)obs + (long)blockIdx.x * 600;
  for (int i = tid; i < 600; i += 256) tksf[i] = o4[i];
  if (tid < NL) rmaxv[tid] = 1.0f / maxvec[tid];
  __syncthreads();

  // ---- decode + ordered compaction ----
  const uint* toks = (const uint*)&tksf[w * 150];
  int cnt = 0;
  #pragma unroll
  for (int r = 0; r < 4; ++r) {
    int m = r * 64 + lane;
    bool valid = false; uint pk = 0;
    if (m < 200) {
      int c = (int)toks[m*3], a = (int)toks[m*3+1], v = (int)toks[m*3+2];
      c = (c == 255) ? 0 : c;  a = (a == 255) ? 0 : a;  v = (v == 255) ? 0 : v;
      int x = (c >> 4) & 15, y = c & 15;
      valid = (x < 11) && (y < 11) && (a < NL);
      pk = ((uint)a << 16) | ((uint)x << 12) | ((uint)y << 8) | (uint)v;
    }
    ull bal = __ballot(valid);
    if (valid) {
      int pos = cnt + __popcll(bal & ((1ull << lane) - 1ull));
      if (pos < 64) klist[w][pos] = pk;
    }
    cnt += __popcll(bal);
  }
  if (cnt > 64) cnt = 64;

  // ---- dedup (last write wins) ----
  uint u = 0; bool alive = false;
  if (lane < cnt) {
    u = klist[w][lane];
    alive = true;
    uint cell = u >> 8;
    for (int t2 = lane + 1; t2 < cnt; ++t2)
      if ((klist[w][t2] >> 8) == cell) { alive = false; break; }
  }
  ull bal2 = __ballot(alive);
  const int n2 = __popcll(bal2);
  if (alive) {
    int pos = __popcll(bal2 & ((1ull << lane) - 1ull));
    klist[w][pos] = u;
  }
  __syncthreads();

  // ---- sparse conv1 (2 oc/lane) + self head (4 j/lane) ----
  float a0[9] = {0,0,0,0,0,0,0,0,0}, a1[9] = {0,0,0,0,0,0,0,0,0};
  float s0 = 0.f, s1 = 0.f, s2 = 0.f, s3 = 0.f;
  for (int t = 0; t < n2; ++t) {
    uint tk = klist[w][t];                 // wave-uniform
    int a = tk >> 16, x = (tk >> 12) & 15, y = (tk >> 8) & 15;
    float fv = (float)(tk & 255u) * rmaxv[a];
    if (x == 5 && y == 5) {
      s0 = fmaf(fv, wself[a*256 + lane      ], s0);
      s1 = fmaf(fv, wself[a*256 + 64  + lane], s1);
      s2 = fmaf(fv, wself[a*256 + 128 + lane], s2);
      s3 = fmaf(fv, wself[a*256 + 192 + lane], s3);
    }
    // closed-form valid output ranges: 3*ox <= x <= 3*ox+4
    int oxlo = (x >= 7) ? ((x + 2) / 3) : ((x >= 4) ? (x - 4 + 2) / 3 : 0);
    oxlo = (x > 4) ? ((x - 4 + 2) / 3) : 0;
    int oxhi = (x / 3 > 2) ? 2 : (x / 3);
    int oylo = (y > 4) ? ((y - 4 + 2) / 3) : 0;
    int oyhi = (y / 3 > 2) ? 2 : (y / 3);
    for (int ox = oxlo; ox <= oxhi; ++ox) {
      int kx = x - 3 * ox;
      for (int oy = oylo; oy <= oyhi; ++oy) {
        int ky = y - 3 * oy;
        const float* wr = w1t + (a*25 + kx*5 + ky) * 128;
        a0[ox*3+oy] = fmaf(fv, wr[lane],      a0[ox*3+oy]);
        a1[ox*3+oy] = fmaf(fv, wr[64 + lane], a1[ox*3+oy]);
      }
    }
  }

  // self_feat -> out hidden[:, 0:256]
  out[HID0 + b*512 + lane      ] = fmaxf(s0 + bself[lane      ], 0.f);
  out[HID0 + b*512 + 64  + lane] = fmaxf(s1 + bself[64  + lane], 0.f);
  out[HID0 + b*512 + 128 + lane] = fmaxf(s2 + bself[128 + lane], 0.f);
  out[HID0 + b*512 + 192 + lane] = fmaxf(s3 + bself[192 + lane], 0.f);

  // h1 bf16, k = oc*9 + p
  float bb0 = bc1[lane], bb1 = bc1[64 + lane];
  #pragma unroll
  for (int p = 0; p < 9; ++p) {
    h1su[w][lane*9 + p]        = f2bf(fmaxf(a0[p] + bb0, 0.f));
    h1su[w][(64 + lane)*9 + p] = f2bf(fmaxf(a1[p] + bb1, 0.f));
  }
  // tiled store: chunk(bb, t, row, 32k); uint i <-> k=2i,2i+1
  const uint* sv = (const uint*)&h1su[w][0];
  const int bbk = (int)(b >> 6), r = (int)(b & 63);
  uint* dstu = (uint*)h1g;
  const long cbase = ((long)bbk * 36) * 64 + r;
  #pragma unroll
  for (int i = lane; i < 576; i += 64) {
    int t = i >> 4;
    dstu[(cbase + (long)t * 64) * 16 + (i & 15)] = sv[i];
  }
}

// ---------------- kernel 2: conv2 + fc via MFMA (N-split waves) ----------------
extern "C" __global__ __launch_bounds__(256)
void k_mlp(const ushort* __restrict__ h1g, const ushort* __restrict__ w2f,
           const float* __restrict__ bc2, const ushort* __restrict__ wfcf,
           const float* __restrict__ bfc, float* __restrict__ out)
{
  __shared__ short  Abuf[2][4][64][8];   // 8 KB, [buf][kchunk][row][8]
  __shared__ ushort h2A[16][64][8];      // 16 KB, [kchunk][row][8]

  const int tid = threadIdx.x, lane = tid & 63, w = tid >> 6;
  const int lo = lane & 15, hi = lane >> 4;
  const int bb = blockIdx.x, b0 = bb * 64;

  const short8* w2fv  = (const short8*)w2f;
  const short8* wfcfv = (const short8*)wfcf;
  const uint4*  A4    = (const uint4*)h1g + (long)bb * 36 * 256;

  // conv2: wave w owns cg = 2w, 2w+1; rows all 64 (4 m-tiles)
  float4_ acc[4][2];
  #pragma unroll
  for (int cgi = 0; cgi < 2; ++cgi) {
    float bv_ = bc2[(2*w + cgi)*16 + lo];
    float4_ t = {bv_, bv_, bv_, bv_};
    #pragma unroll
    for (int m = 0; m < 4; ++m) acc[m][cgi] = t;
  }

  uint4 rA = A4[tid];
  for (int t = 0; t < 36; ++t) {
    const int cur = t & 1;
    *(uint4*)&Abuf[cur][tid & 3][tid >> 2][0] = rA;
    if (t + 1 < 36) rA = A4[(t + 1) * 256 + tid];
    __syncthreads();
    short8 af[4];
    #pragma unroll
    for (int m = 0; m < 4; ++m)
      af[m] = *(const short8*)&Abuf[cur][hi][m*16 + lo][0];
    #pragma unroll
    for (int cgi = 0; cgi < 2; ++cgi) {
      short8 bf = w2fv[(t*8 + 2*w + cgi)*64 + lane];
      #pragma unroll
      for (int m = 0; m < 4; ++m)
        acc[m][cgi] = __builtin_amdgcn_mfma_f32_16x16x32_bf16(af[m], bf, acc[m][cgi], 0, 0, 0);
    }
  }
  __syncthreads();

  // h2 -> LDS bf16 (A-frag layout), cols (2w..2w+1)*16+lo, rows m*16+hi*4+q
  #pragma unroll
  for (int cgi = 0; cgi < 2; ++cgi) {
    int col = (2*w + cgi)*16 + lo;
    #pragma unroll
    for (int m = 0; m < 4; ++m)
      #pragma unroll
      for (int q = 0; q < 4; ++q) {
        int R = m*16 + hi*4 + q;
        h2A[col >> 3][R][col & 7] = f2bf(fmaxf(acc[m][cgi][q], 0.f));
      }
  }
  __syncthreads();

  // fc: wave w owns cg = 4w..4w+3
  float4_ acc2[4][4];
  #pragma unroll
  for (int cgi = 0; cgi < 4; ++cgi) {
    float bv_ = bfc[(4*w + cgi)*16 + lo];
    float4_ t = {bv_, bv_, bv_, bv_};
    #pragma unroll
    for (int m = 0; m < 4; ++m) acc2[m][cgi] = t;
  }
  #pragma unroll
  for (int ks = 0; ks < 4; ++ks) {
    short8 af[4];
    #pragma unroll
    for (int m = 0; m < 4; ++m)
      af[m] = *(const short8*)&h2A[ks*4 + hi][m*16 + lo][0];
    #pragma unroll
    for (int cgi = 0; cgi < 4; ++cgi) {
      short8 bf = wfcfv[(ks*16 + 4*w + cgi)*64 + lane];
      #pragma unroll
      for (int m = 0; m < 4; ++m)
        acc2[m][cgi] = __builtin_amdgcn_mfma_f32_16x16x32_bf16(af[m], bf, acc2[m][cgi], 0, 0, 0);
    }
  }

  // cnn_feat -> out hidden[:, 256:512]
  #pragma unroll
  for (int cgi = 0; cgi < 4; ++cgi) {
    int col = (4*w + cgi)*16 + lo;
    #pragma unroll
    for (int m = 0; m < 4; ++m)
      #pragma unroll
      for (int q = 0; q < 4; ++q) {
        int R = m*16 + hi*4 + q;
        out[HID0 + (long)(b0 + R)*512 + 256 + col] = fmaxf(acc2[m][cgi][q], 0.f);
      }
  }
}

// ---------------- kernel 3: heads via MFMA ----------------
extern "C" __global__ __launch_bounds__(256)
void k_heads(const ushort* __restrict__ whf,
             const float* __restrict__ ba0, const float* __restrict__ ba1,
             const float* __restrict__ bv, float* __restrict__ out)
{
  __shared__ ushort hidA[64][64][8];     // 64 KB, [row][chunk^swz][8]

  const int tid = threadIdx.x, lane = tid & 63, w = tid >> 6;
  const int lo = lane & 15, hi = lane >> 4;
  const int b0 = blockIdx.x * 64;

  // stage hidden (fp32 -> bf16), XOR-swizzled chunks
  const uint4* hv = (const uint4*)(out + HID0);
  for (int it = 0; it < 16; ++it) {
    int gid = it * 256 + tid;
    int r = gid >> 6, c = gid & 63;
    long base = (long)(b0 + r) * 128 + c * 2;
    uint4 u0 = hv[base], u1 = hv[base + 1];
    const float* f0 = (const float*)&u0;
    const float* f1 = (const float*)&u1;
    uint4 o = { (uint)f2bf(f0[0]) | ((uint)f2bf(f0[1]) << 16),
                (uint)f2bf(f0[2]) | ((uint)f2bf(f0[3]) << 16),
                (uint)f2bf(f1[0]) | ((uint)f2bf(f1[1]) << 16),
                (uint)f2bf(f1[2]) | ((uint)f2bf(f1[3]) << 16) };
    *(uint4*)&hidA[r][c ^ (r & 7)][0] = o;
  }
  __syncthreads();

  const short8* whfv = (const short8*)whf;
  float4_ acc[2];
  #pragma unroll
  for (int cg = 0; cg < 2; ++cg) {
    int col = cg*16 + lo;
    float bias = (col < 9) ? ba0[col] : (col < 19) ? ba1[col - 9]
               : (col == 19) ? bv[0] : 0.f;
    float4_ t = {bias, bias, bias, bias};
    acc[cg] = t;
  }

  const int row = w*16 + lo;
  #pragma unroll
  for (int ks = 0; ks < 16; ++ks) {
    short8 af = *(const short8*)&hidA[row][(ks*4 + hi) ^ (lo & 7)][0];
    #pragma unroll
    for (int cg = 0; cg < 2; ++cg) {
      short8 bf = whfv[(ks*2 + cg)*64 + lane];
      acc[cg] = __builtin_amdgcn_mfma_f32_16x16x32_bf16(af, bf, acc[cg], 0, 0, 0);
    }
  }

  #pragma unroll
  for (int cg = 0; cg < 2; ++cg) {
    int col = cg*16 + lo;
    #pragma unroll
    for (int q = 0; q < 4; ++q) {
      long R = b0 + w*16 + hi*4 + q;
      float v = acc[cg][q];
      if (col < 9)        out[R*9 + col] = v;
      else if (col < 19)  out[(long)B_TOT*9 + R*10 + (col - 9)] = v;
      else if (col == 19) out[(long)B_TOT*19 + R] = v;
    }
  }
}

extern "C" void kernel_launch(void* const* d_in, const int* in_sizes, int n_in,
                              void* d_out, int out_size, void* d_ws, size_t ws_size,
                              hipStream_t stream) {
  const int* obs      = (const int*)d_in[0];
  const float* maxvec = (const float*)d_in[1];
  const float* wc1    = (const float*)d_in[2];
  const float* bc1    = (const float*)d_in[3];
  const float* wc2    = (const float*)d_in[4];
  const float* bc2    = (const float*)d_in[5];
  const float* wfc    = (const float*)d_in[6];
  const float* bfc    = (const float*)d_in[7];
  const float* wself  = (const float*)d_in[8];
  const float* bself  = (const float*)d_in[9];
  const float* wa0    = (const float*)d_in[10];
  const float* ba0    = (const float*)d_in[11];
  const float* wa1    = (const float*)d_in[12];
  const float* ba1    = (const float*)d_in[13];
  const float* wv     = (const float*)d_in[14];
  const float* bv     = (const float*)d_in[15];
  float* out          = (float*)d_out;

  char* ws = (char*)d_ws;
  ushort* w2f  = (ushort*)(ws + W2F_OFF);
  ushort* wfcf = (ushort*)(ws + WFCF_OFF);
  ushort* whf  = (ushort*)(ws + WHF_OFF);
  float*  w1t  = (float*)(ws + W1T_OFF);
  ushort* h1g  = (ushort*)(ws + H1_OFF);

  k_prep  <<<dim3(371),      dim3(256), 0, stream>>>(wc1, wc2, wfc, wa0, wa1, wv,
                                                     w2f, wfcf, whf, w1t);
  k_encode<<<dim3(B_TOT/4),  dim3(256), 0, stream>>>(obs, maxvec, w1t, bc1,
                                                     wself, bself, out, h1g);
  k_mlp   <<<dim3(B_TOT/64), dim3(256), 0, stream>>>(h1g, w2f, bc2, wfcf, bfc, out);
  k_heads <<<dim3(B_TOT/64), dim3(256), 0, stream>>>(whf, ba0, ba1, bv, out);
}

// Round 6
// 108.302 us; speedup vs baseline: 30.8487x; 1.2610x over previous
//
#include <hip/hip_runtime.h>
#include <hip/hip_bf16.h>

typedef unsigned int uint;
typedef unsigned short ushort;
typedef unsigned long long ull;
typedef __attribute__((ext_vector_type(8))) short short8;
typedef __attribute__((ext_vector_type(4))) float float4_;

#define B_TOT 32768
#define NL    22
#define HID0  ((long)B_TOT * 20)

// ws layout (bytes), 16B aligned
#define W2F_OFF  0          // conv2 B-frags bf16: 36*8*64*16B  = 294,912
#define WFCF_OFF 294912     // fc    B-frags bf16: 4*16*64*16B  = 65,536
#define WHF_OFF  360448     // heads B-frags bf16: 16*2*64*16B  = 32,768
#define W1T_OFF  393216     // conv1 W^T f32: 550*128*4          = 281,600
#define H1_OFF   674816     // h1 tiled bf16: 512*36*64*32*2     = 75,497,472
// total 76,172,288

__device__ __forceinline__ ushort f2bf(float v) {
  uint x = __float_as_uint(v);
  x += 0x7fffu + ((x >> 16) & 1u);
  return (ushort)(x >> 16);
}

// ---------------- prologue: weight repack ----------------
extern "C" __global__ __launch_bounds__(256)
void k_prep(const float* __restrict__ wc1, const float* __restrict__ wc2,
            const float* __restrict__ wfc,
            const float* __restrict__ wa0, const float* __restrict__ wa1,
            const float* __restrict__ wv,
            ushort* __restrict__ w2f, ushort* __restrict__ wfcf,
            ushort* __restrict__ whf, float* __restrict__ w1t)
{
  int i = blockIdx.x * 256 + threadIdx.x;
  if (i < 18432) {                       // conv2: B[k][col] = wc2[col][k]
    int l = i & 63, cg = (i >> 6) & 7, ks = i >> 9;
    int col = cg * 16 + (l & 15), kb = ks * 32 + (l >> 4) * 8;
    ushort t[8];
    #pragma unroll
    for (int j = 0; j < 8; ++j) t[j] = f2bf(wc2[col * 1152 + kb + j]);
    uint4 o = { (uint)t[0]|((uint)t[1]<<16), (uint)t[2]|((uint)t[3]<<16),
                (uint)t[4]|((uint)t[5]<<16), (uint)t[6]|((uint)t[7]<<16) };
    ((uint4*)w2f)[i] = o;
  } else if (i < 22528) {                // fc: B[k][col] = wfc[k][col]
    int i2 = i - 18432;
    int l = i2 & 63, cg = (i2 >> 6) & 15, ks = i2 >> 10;
    int col = cg * 16 + (l & 15), kb = ks * 32 + (l >> 4) * 8;
    ushort t[8];
    #pragma unroll
    for (int j = 0; j < 8; ++j) t[j] = f2bf(wfc[(kb + j) * 256 + col]);
    uint4 o = { (uint)t[0]|((uint)t[1]<<16), (uint)t[2]|((uint)t[3]<<16),
                (uint)t[4]|((uint)t[5]<<16), (uint)t[6]|((uint)t[7]<<16) };
    ((uint4*)wfcf)[i2] = o;
  } else if (i < 24576) {                // heads: cols 0..8 wa0, 9..18 wa1, 19 wv
    int i2 = i - 22528;
    int l = i2 & 63, cg = (i2 >> 6) & 1, ks = i2 >> 7;
    int col = cg * 16 + (l & 15), kb = ks * 32 + (l >> 4) * 8;
    ushort t[8];
    #pragma unroll
    for (int j = 0; j < 8; ++j) {
      int k = kb + j;
      float v = (col < 9)  ? wa0[k*9 + col]
              : (col < 19) ? wa1[k*10 + (col - 9)]
              : (col == 19) ? wv[k] : 0.f;
      t[j] = f2bf(v);
    }
    uint4 o = { (uint)t[0]|((uint)t[1]<<16), (uint)t[2]|((uint)t[3]<<16),
                (uint)t[4]|((uint)t[5]<<16), (uint)t[6]|((uint)t[7]<<16) };
    ((uint4*)whf)[i2] = o;
  } else if (i < 24576 + 70400) {        // w1t[r*128+oc] = wc1[oc][r]
    int j = i - 24576;
    int oc = j & 127, r = j >> 7;
    w1t[j] = wc1[oc * 550 + r];
  }
}

// ---------------- kernel 1: tokens -> sparse conv1 + self head ----------------
extern "C" __global__ __launch_bounds__(256)
void k_encode(const int* __restrict__ obs, const float* __restrict__ maxvec,
              const float* __restrict__ w1t, const float* __restrict__ bc1,
              const float* __restrict__ wself, const float* __restrict__ bself,
              float* __restrict__ out, ushort* __restrict__ h1g)
{
  __shared__ uint4  tksf[600];          // 4 samples x 150 uint4
  __shared__ uint   klist[4][64];
  __shared__ ushort h1su[4][1152];
  __shared__ float  rmaxv[NL];

  const int tid = threadIdx.x, lane = tid & 63, w = tid >> 6;
  const long b = (long)blockIdx.x * 4 + w;

  const uint4* o4 = (const uint4*)obs + (long)blockIdx.x * 600;
  for (int i = tid; i < 600; i += 256) tksf[i] = o4[i];
  if (tid < NL) rmaxv[tid] = 1.0f / maxvec[tid];
  __syncthreads();

  // ---- decode + ordered compaction ----
  const uint* toks = (const uint*)&tksf[w * 150];
  int cnt = 0;
  #pragma unroll
  for (int r = 0; r < 4; ++r) {
    int m = r * 64 + lane;
    bool valid = false; uint pk = 0;
    if (m < 200) {
      int c = (int)toks[m*3], a = (int)toks[m*3+1], v = (int)toks[m*3+2];
      c = (c == 255) ? 0 : c;  a = (a == 255) ? 0 : a;  v = (v == 255) ? 0 : v;
      int x = (c >> 4) & 15, y = c & 15;
      valid = (x < 11) && (y < 11) && (a < NL);
      pk = ((uint)a << 16) | ((uint)x << 12) | ((uint)y << 8) | (uint)v;
    }
    ull bal = __ballot(valid);
    if (valid) {
      int pos = cnt + __popcll(bal & ((1ull << lane) - 1ull));
      if (pos < 64) klist[w][pos] = pk;
    }
    cnt += __popcll(bal);
  }
  if (cnt > 64) cnt = 64;

  // ---- dedup (last write wins) ----
  uint u = 0; bool alive = false;
  if (lane < cnt) {
    u = klist[w][lane];
    alive = true;
    uint cell = u >> 8;
    for (int t2 = lane + 1; t2 < cnt; ++t2)
      if ((klist[w][t2] >> 8) == cell) { alive = false; break; }
  }
  ull bal2 = __ballot(alive);
  const int n2 = __popcll(bal2);
  if (alive) {
    int pos = __popcll(bal2 & ((1ull << lane) - 1ull));
    klist[w][pos] = u;
  }
  __syncthreads();

  // ---- sparse conv1 (2 oc/lane) + self head (4 j/lane) ----
  // NOTE: all accumulator indices compile-time (unrolled + predication);
  // runtime-indexed reg arrays lower to cndmask cascades (round-5 regression).
  float a0[9] = {0,0,0,0,0,0,0,0,0}, a1[9] = {0,0,0,0,0,0,0,0,0};
  float s0 = 0.f, s1 = 0.f, s2 = 0.f, s3 = 0.f;
  uint tk = klist[w][0];
  for (int t = 0; t < n2; ++t) {
    uint cur = tk;                              // wave-uniform
    tk = klist[w][(t + 1) & 63];                // prefetch next
    int a = cur >> 16, x = (cur >> 12) & 15, y = (cur >> 8) & 15;
    float fv = (float)(cur & 255u) * rmaxv[a];
    if (x == 5 && y == 5) {
      s0 = fmaf(fv, wself[a*256 + lane      ], s0);
      s1 = fmaf(fv, wself[a*256 + 64  + lane], s1);
      s2 = fmaf(fv, wself[a*256 + 128 + lane], s2);
      s3 = fmaf(fv, wself[a*256 + 192 + lane], s3);
    }
    #pragma unroll
    for (int ox = 0; ox < 3; ++ox) {
      int kx = x - 3 * ox;
      if ((unsigned)kx > 4u) continue;          // wave-uniform branch
      #pragma unroll
      for (int oy = 0; oy < 3; ++oy) {
        int ky = y - 3 * oy;
        if ((unsigned)ky > 4u) continue;
        const float* wr = w1t + (a*25 + kx*5 + ky) * 128;
        a0[ox*3+oy] = fmaf(fv, wr[lane],      a0[ox*3+oy]);
        a1[ox*3+oy] = fmaf(fv, wr[64 + lane], a1[ox*3+oy]);
      }
    }
  }

  // self_feat -> out hidden[:, 0:256]
  out[HID0 + b*512 + lane      ] = fmaxf(s0 + bself[lane      ], 0.f);
  out[HID0 + b*512 + 64  + lane] = fmaxf(s1 + bself[64  + lane], 0.f);
  out[HID0 + b*512 + 128 + lane] = fmaxf(s2 + bself[128 + lane], 0.f);
  out[HID0 + b*512 + 192 + lane] = fmaxf(s3 + bself[192 + lane], 0.f);

  // h1 bf16, k = oc*9 + p
  float bb0 = bc1[lane], bb1 = bc1[64 + lane];
  #pragma unroll
  for (int p = 0; p < 9; ++p) {
    h1su[w][lane*9 + p]        = f2bf(fmaxf(a0[p] + bb0, 0.f));
    h1su[w][(64 + lane)*9 + p] = f2bf(fmaxf(a1[p] + bb1, 0.f));
  }
  // tiled store for k_mlp: chunk(bb, t, row, 32k)
  const uint* sv = (const uint*)&h1su[w][0];
  const int bbk = (int)(b >> 6), r = (int)(b & 63);
  uint* dstu = (uint*)h1g;
  const long cbase = ((long)bbk * 36) * 64 + r;
  #pragma unroll
  for (int i = lane; i < 576; i += 64) {
    int t = i >> 4;
    dstu[(cbase + (long)t * 64) * 16 + (i & 15)] = sv[i];
  }
}

// ---------------- kernel 2: conv2 + fc + heads via MFMA ----------------
extern "C" __global__ __launch_bounds__(256)
void k_mlp(const ushort* __restrict__ h1g, const ushort* __restrict__ w2f,
           const float* __restrict__ bc2, const ushort* __restrict__ wfcf,
           const float* __restrict__ bfc, const ushort* __restrict__ whf,
           const float* __restrict__ ba0, const float* __restrict__ ba1,
           const float* __restrict__ bv, float* __restrict__ out)
{
  __shared__ short  Abuf[2][4][64][8];   // 8 KB
  __shared__ ushort h2A[16][64][8];      // 16 KB

  const int tid = threadIdx.x, lane = tid & 63, w = tid >> 6;
  const int lo = lane & 15, hi = lane >> 4;
  const int bb = blockIdx.x, b0 = bb * 64;

  const short8* w2fv  = (const short8*)w2f;
  const short8* wfcfv = (const short8*)wfcf;
  const uint4*  A4    = (const uint4*)h1g + (long)bb * 36 * 256;

  // ---- conv2: wave w owns cols (2w,2w+1)*16, all 64 rows ----
  float4_ acc[4][2];
  #pragma unroll
  for (int cgi = 0; cgi < 2; ++cgi) {
    float bv_ = bc2[(2*w + cgi)*16 + lo];
    float4_ t = {bv_, bv_, bv_, bv_};
    #pragma unroll
    for (int m = 0; m < 4; ++m) acc[m][cgi] = t;
  }

  uint4 rA = A4[tid];
  for (int t = 0; t < 36; ++t) {
    const int cur = t & 1;
    *(uint4*)&Abuf[cur][tid & 3][tid >> 2][0] = rA;
    if (t + 1 < 36) rA = A4[(t + 1) * 256 + tid];
    __syncthreads();
    short8 af[4];
    #pragma unroll
    for (int m = 0; m < 4; ++m)
      af[m] = *(const short8*)&Abuf[cur][hi][m*16 + lo][0];
    #pragma unroll
    for (int cgi = 0; cgi < 2; ++cgi) {
      short8 bf = w2fv[(t*8 + 2*w + cgi)*64 + lane];
      #pragma unroll
      for (int m = 0; m < 4; ++m)
        acc[m][cgi] = __builtin_amdgcn_mfma_f32_16x16x32_bf16(af[m], bf, acc[m][cgi], 0, 0, 0);
    }
  }
  __syncthreads();

  // h2 -> LDS bf16 (A-frag layout)
  #pragma unroll
  for (int cgi = 0; cgi < 2; ++cgi) {
    int col = (2*w + cgi)*16 + lo;
    #pragma unroll
    for (int m = 0; m < 4; ++m)
      #pragma unroll
      for (int q = 0; q < 4; ++q) {
        int R = m*16 + hi*4 + q;
        h2A[col >> 3][R][col & 7] = f2bf(fmaxf(acc[m][cgi][q], 0.f));
      }
  }
  __syncthreads();

  // ---- fc: wave w owns cols (4w..4w+3)*16 ----
  float4_ acc2[4][4];
  #pragma unroll
  for (int cgi = 0; cgi < 4; ++cgi) {
    float bv_ = bfc[(4*w + cgi)*16 + lo];
    float4_ t = {bv_, bv_, bv_, bv_};
    #pragma unroll
    for (int m = 0; m < 4; ++m) acc2[m][cgi] = t;
  }
  #pragma unroll
  for (int ks = 0; ks < 4; ++ks) {
    short8 af[4];
    #pragma unroll
    for (int m = 0; m < 4; ++m)
      af[m] = *(const short8*)&h2A[ks*4 + hi][m*16 + lo][0];
    #pragma unroll
    for (int cgi = 0; cgi < 4; ++cgi) {
      short8 bf = wfcfv[(ks*16 + 4*w + cgi)*64 + lane];
      #pragma unroll
      for (int m = 0; m < 4; ++m)
        acc2[m][cgi] = __builtin_amdgcn_mfma_f32_16x16x32_bf16(af[m], bf, acc2[m][cgi], 0, 0, 0);
    }
  }

  // cnn_feat -> out hidden[:, 256:512]
  #pragma unroll
  for (int cgi = 0; cgi < 4; ++cgi) {
    int col = (4*w + cgi)*16 + lo;
    #pragma unroll
    for (int m = 0; m < 4; ++m)
      #pragma unroll
      for (int q = 0; q < 4; ++q) {
        int R = m*16 + hi*4 + q;
        out[HID0 + (long)(b0 + R)*512 + 256 + col] = fmaxf(acc2[m][cgi][q], 0.f);
      }
  }
  __syncthreads();   // drain stores; hidden rows b0..b0+63 now visible block-wide

  // ---- heads: wave w owns rows w*16..w*16+15, cols 0..31 ----
  const short8* whfv = (const short8*)whf;
  float4_ acc3[2];
  #pragma unroll
  for (int cg = 0; cg < 2; ++cg) {
    int col = cg*16 + lo;
    float bias = (col < 9) ? ba0[col] : (col < 19) ? ba1[col - 9]
               : (col == 19) ? bv[0] : 0.f;
    float4_ t = {bias, bias, bias, bias};
    acc3[cg] = t;
  }

  const float* hrow = out + HID0 + (long)(b0 + w*16 + lo) * 512;
  #pragma unroll
  for (int ks = 0; ks < 16; ++ks) {
    float4_ f0 = *(const float4_*)(hrow + ks*32 + hi*8);
    float4_ f1 = *(const float4_*)(hrow + ks*32 + hi*8 + 4);
    union { short8 s; ushort u[8]; } afu;
    afu.u[0] = f2bf(f0[0]); afu.u[1] = f2bf(f0[1]);
    afu.u[2] = f2bf(f0[2]); afu.u[3] = f2bf(f0[3]);
    afu.u[4] = f2bf(f1[0]); afu.u[5] = f2bf(f1[1]);
    afu.u[6] = f2bf(f1[2]); afu.u[7] = f2bf(f1[3]);
    #pragma unroll
    for (int cg = 0; cg < 2; ++cg) {
      short8 bf = whfv[(ks*2 + cg)*64 + lane];
      acc3[cg] = __builtin_amdgcn_mfma_f32_16x16x32_bf16(afu.s, bf, acc3[cg], 0, 0, 0);
    }
  }

  #pragma unroll
  for (int cg = 0; cg < 2; ++cg) {
    int col = cg*16 + lo;
    #pragma unroll
    for (int q = 0; q < 4; ++q) {
      long R = b0 + w*16 + hi*4 + q;
      float v = acc3[cg][q];
      if (col < 9)        out[R*9 + col] = v;
      else if (col < 19)  out[(long)B_TOT*9 + R*10 + (col - 9)] = v;
      else if (col == 19) out[(long)B_TOT*19 + R] = v;
    }
  }
}

extern "C" void kernel_launch(void* const* d_in, const int* in_sizes, int n_in,
                              void* d_out, int out_size, void* d_ws, size_t ws_size,
                              hipStream_t stream) {
  const int* obs      = (const int*)d_in[0];
  const float* maxvec = (const float*)d_in[1];
  const float* wc1    = (const float*)d_in[2];
  const float* bc1    = (const float*)d_in[3];
  const float* wc2    = (const float*)d_in[4];
  const float* bc2    = (const float*)d_in[5];
  const float* wfc    = (const float*)d_in[6];
  const float* bfc    = (const float*)d_in[7];
  const float* wself  = (const float*)d_in[8];
  const float* bself  = (const float*)d_in[9];
  const float* wa0    = (const float*)d_in[10];
  const float* ba0    = (const float*)d_in[11];
  const float* wa1    = (const float*)d_in[12];
  const float* ba1    = (const float*)d_in[13];
  const float* wv     = (const float*)d_in[14];
  const float* bv     = (const float*)d_in[15];
  float* out          = (float*)d_out;

  char* ws = (char*)d_ws;
  ushort* w2f  = (ushort*)(ws + W2F_OFF);
  ushort* wfcf = (ushort*)(ws + WFCF_OFF);
  ushort* whf  = (ushort*)(ws + WHF_OFF);
  float*  w1t  = (float*)(ws + W1T_OFF);
  ushort* h1g  = (ushort*)(ws + H1_OFF);

  k_prep  <<<dim3(371),      dim3(256), 0, stream>>>(wc1, wc2, wfc, wa0, wa1, wv,
                                                     w2f, wfcf, whf, w1t);
  k_encode<<<dim3(B_TOT/4),  dim3(256), 0, stream>>>(obs, maxvec, w1t, bc1,
                                                     wself, bself, out, h1g);
  k_mlp   <<<dim3(B_TOT/64), dim3(256), 0, stream>>>(h1g, w2f, bc2, wfcf, bfc,
                                                     whf, ba0, ba1, bv, out);
}